// Round 2
// baseline (1471.899 us; speedup 1.0000x reference)
//
#include <hip/hip_runtime.h>
#include <stdint.h>

// out[index[i]] += value[i], duplicates accumulate. N = 2^24 table, M = 2^25 updates.
// Binned two-pass: pack (local_idx:14 | value:10) into u32 per update into per-bucket
// regions in d_ws, then one block per bucket accumulates in LDS and writes out=input+acc.

#define LOGSLICE  14
#define SLICE     (1 << LOGSLICE)   // 16384 entries / bucket = 64 KiB LDS slice
#define NB        1024              // buckets = 2^24 / 2^14
#define CAP       36864             // per-bucket capacity: mean 32768 + 22 sigma (cannot overflow)
#define CURSTRIDE 16                // cursors padded to 64B lines (avoid same-line atomic serialization)

// ---------------- binned path ----------------

__global__ void ip_zero_cursors(uint32_t* __restrict__ cur) {
    cur[threadIdx.x * CURSTRIDE] = 0;   // 1 block x 1024 threads
}

__global__ void ip_scatter_pairs(const int4* __restrict__ index4, const int4* __restrict__ value4,
                                 uint32_t* __restrict__ cur, uint32_t* __restrict__ pairs,
                                 int m4) {
    int i = blockIdx.x * blockDim.x + threadIdx.x;
    if (i >= m4) return;
    int4 id = index4[i];
    int4 v  = value4[i];
#define PUT(c)                                                                  \
    {                                                                           \
        uint32_t idx = (uint32_t)id.c;                                          \
        uint32_t val = (uint32_t)v.c;                                           \
        uint32_t b   = idx >> LOGSLICE;                                         \
        uint32_t pos = atomicAdd(&cur[b * CURSTRIDE], 1u);                      \
        pairs[(size_t)b * CAP + pos] = (val << LOGSLICE) | (idx & (SLICE - 1)); \
    }
    PUT(x) PUT(y) PUT(z) PUT(w)
#undef PUT
}

__global__ __launch_bounds__(512) void ip_accumulate(const uint32_t* __restrict__ pairs,
                                                     const uint32_t* __restrict__ cur,
                                                     const int4* __restrict__ input4,
                                                     int4* __restrict__ out4) {
    __shared__ uint32_t acc[SLICE];     // 64 KiB
    const int b = blockIdx.x;

    for (int j = threadIdx.x; j < SLICE; j += blockDim.x) acc[j] = 0;
    __syncthreads();

    const uint32_t cnt = cur[b * CURSTRIDE];
    const uint32_t* __restrict__ p = pairs + (size_t)b * CAP;

    // vectorized replay of this bucket's packed updates
    const uint32_t cnt4 = cnt >> 2;
    const uint4* __restrict__ p4 = (const uint4*)p;
    for (uint32_t j = threadIdx.x; j < cnt4; j += blockDim.x) {
        uint4 pk = p4[j];
        atomicAdd(&acc[pk.x & (SLICE - 1)], pk.x >> LOGSLICE);
        atomicAdd(&acc[pk.y & (SLICE - 1)], pk.y >> LOGSLICE);
        atomicAdd(&acc[pk.z & (SLICE - 1)], pk.z >> LOGSLICE);
        atomicAdd(&acc[pk.w & (SLICE - 1)], pk.w >> LOGSLICE);
    }
    for (uint32_t j = (cnt4 << 2) + threadIdx.x; j < cnt; j += blockDim.x) {
        uint32_t pk = p[j];
        atomicAdd(&acc[pk & (SLICE - 1)], pk >> LOGSLICE);
    }
    __syncthreads();

    // out = input + acc (this also serves as the table copy)
    const int base4 = b * (SLICE / 4);
    for (int j = threadIdx.x; j < SLICE / 4; j += blockDim.x) {
        int4 in = input4[base4 + j];
        in.x += (int)acc[j * 4 + 0];
        in.y += (int)acc[j * 4 + 1];
        in.z += (int)acc[j * 4 + 2];
        in.w += (int)acc[j * 4 + 3];
        out4[base4 + j] = in;
    }
}

// ---------------- fallback path (direct atomics) ----------------

__global__ void ip_copy_kernel(const int4* __restrict__ in, int4* __restrict__ out, int n4) {
    int stride = gridDim.x * blockDim.x;
    for (int i = blockIdx.x * blockDim.x + threadIdx.x; i < n4; i += stride)
        out[i] = in[i];
}

__global__ void ip_scatter_kernel(const int4* __restrict__ index, const int4* __restrict__ value,
                                  int* __restrict__ out, int m4) {
    int i = blockIdx.x * blockDim.x + threadIdx.x;
    if (i >= m4) return;
    int4 id = index[i];
    int4 v  = value[i];
    atomicAdd(&out[id.x], v.x);
    atomicAdd(&out[id.y], v.y);
    atomicAdd(&out[id.z], v.z);
    atomicAdd(&out[id.w], v.w);
}

extern "C" void kernel_launch(void* const* d_in, const int* in_sizes, int n_in,
                              void* d_out, int out_size, void* d_ws, size_t ws_size,
                              hipStream_t stream) {
    const int* input = (const int*)d_in[0];
    const int* index = (const int*)d_in[1];
    const int* value = (const int*)d_in[2];
    int* out = (int*)d_out;

    const int N = in_sizes[0];
    const int M = in_sizes[1];
    const int m4 = M / 4;

    const size_t cur_bytes  = (size_t)NB * CURSTRIDE * sizeof(uint32_t);  // 64 KiB
    const size_t need_bytes = cur_bytes + (size_t)NB * CAP * sizeof(uint32_t); // ~151 MB

    const bool shapes_ok = (N == NB * SLICE) && (M % 4 == 0);

    if (shapes_ok && ws_size >= need_bytes) {
        uint32_t* cur   = (uint32_t*)d_ws;
        uint32_t* pairs = (uint32_t*)((char*)d_ws + cur_bytes);

        ip_zero_cursors<<<1, NB, 0, stream>>>(cur);

        const int block = 256;
        const int grid_scatter = (m4 + block - 1) / block;   // 32768
        ip_scatter_pairs<<<grid_scatter, block, 0, stream>>>(
            (const int4*)index, (const int4*)value, cur, pairs, m4);

        ip_accumulate<<<NB, 512, 0, stream>>>(
            pairs, cur, (const int4*)input, (int4*)out);
    } else {
        const int n4 = N / 4;
        ip_copy_kernel<<<2048, 256, 0, stream>>>((const int4*)input, (int4*)d_out, n4);
        const int grid_scatter = (m4 + 255) / 256;
        ip_scatter_kernel<<<grid_scatter, 256, 0, stream>>>(
            (const int4*)index, (const int4*)value, out, m4);
    }
}

// Round 3
// 1285.113 us; speedup vs baseline: 1.1453x; 1.1453x over previous
//
#include <hip/hip_runtime.h>
#include <stdint.h>

// out[index[i]] += value[i], duplicates accumulate. N = 2^24 table, M = 2^25 updates.
// Direct-atomic path restructured for maximum outstanding atomics per wave:
// one thread = 16 updates, all loads issued first (coalesced via stride-T layout),
// then 16 fire-and-forget global atomics, then the wave ends. No loop-carried
// vmcnt dependency ever forces the atomics to drain -> latency-hiding via MLP.

__global__ void ip_copy_kernel(const int4* __restrict__ in, int4* __restrict__ out, int n4) {
    int stride = gridDim.x * blockDim.x;
    for (int i = blockIdx.x * blockDim.x + threadIdx.x; i < n4; i += stride)
        out[i] = in[i];
}

// T = total threads = m4/4. Thread t handles int4 elements {t, t+T, t+2T, t+3T}
// of both index and value (each load instruction is perfectly lane-coalesced).
__global__ __launch_bounds__(256) void ip_scatter16_kernel(const int4* __restrict__ index4,
                                                           const int4* __restrict__ value4,
                                                           int* __restrict__ out, int T) {
    int t = blockIdx.x * blockDim.x + threadIdx.x;
    if (t >= T) return;

    int4 id0 = index4[t + 0 * T];
    int4 id1 = index4[t + 1 * T];
    int4 id2 = index4[t + 2 * T];
    int4 id3 = index4[t + 3 * T];
    int4 v0  = value4[t + 0 * T];
    int4 v1  = value4[t + 1 * T];
    int4 v2  = value4[t + 2 * T];
    int4 v3  = value4[t + 3 * T];

    atomicAdd(&out[id0.x], v0.x);
    atomicAdd(&out[id0.y], v0.y);
    atomicAdd(&out[id0.z], v0.z);
    atomicAdd(&out[id0.w], v0.w);
    atomicAdd(&out[id1.x], v1.x);
    atomicAdd(&out[id1.y], v1.y);
    atomicAdd(&out[id1.z], v1.z);
    atomicAdd(&out[id1.w], v1.w);
    atomicAdd(&out[id2.x], v2.x);
    atomicAdd(&out[id2.y], v2.y);
    atomicAdd(&out[id2.z], v2.z);
    atomicAdd(&out[id2.w], v2.w);
    atomicAdd(&out[id3.x], v3.x);
    atomicAdd(&out[id3.y], v3.y);
    atomicAdd(&out[id3.z], v3.z);
    atomicAdd(&out[id3.w], v3.w);
}

// Fallback for odd sizes: simple grid-stride atomic scatter (scalar).
__global__ void ip_scatter1_kernel(const int* __restrict__ index, const int* __restrict__ value,
                                   int* __restrict__ out, int m) {
    int stride = gridDim.x * blockDim.x;
    for (int i = blockIdx.x * blockDim.x + threadIdx.x; i < m; i += stride)
        atomicAdd(&out[index[i]], value[i]);
}

extern "C" void kernel_launch(void* const* d_in, const int* in_sizes, int n_in,
                              void* d_out, int out_size, void* d_ws, size_t ws_size,
                              hipStream_t stream) {
    const int* input = (const int*)d_in[0];
    const int* index = (const int*)d_in[1];
    const int* value = (const int*)d_in[2];
    int* out = (int*)d_out;

    const int N = in_sizes[0];
    const int M = in_sizes[1];

    // table copy (out = input)
    const int n4 = N / 4;
    ip_copy_kernel<<<2048, 256, 0, stream>>>((const int4*)input, (int4*)d_out, n4);

    if (M % 16 == 0) {
        const int T = M / 16;          // threads; each does 16 updates
        const int block = 256;
        const int grid = (T + block - 1) / block;   // 8192 for M=2^25
        ip_scatter16_kernel<<<grid, block, 0, stream>>>(
            (const int4*)index, (const int4*)value, out, T);
    } else {
        ip_scatter1_kernel<<<2048, 256, 0, stream>>>(index, value, out, M);
    }
}

// Round 4
// 391.696 us; speedup vs baseline: 3.7578x; 3.2809x over previous
//
#include <hip/hip_runtime.h>
#include <stdint.h>

// out[index[i]] += value[i], duplicates accumulate. N = 2^24 table, M = 2^25 updates.
// Atomic-free counting sort: global atomicAdd is capped ~26 G/s on gfx950 (rounds 1-3:
// 33.5M atomics = ~1.27 ms regardless of pattern/MLP; WRITE_SIZE = M*32B write-through).
// So: bin updates by 14-bit bucket with exact precomputed offsets (LDS atomics only),
// then accumulate each 64KiB slice in LDS and write out = input + acc.

#define LOGSLICE  14
#define SLICE     (1 << LOGSLICE)     // 16384 entries per bucket
#define NB        1024                // buckets = 2^24 / 2^14
#define B_UPD     8192                // updates per bin/count block
#define B_THR     256

// ---------- K1: per-block bucket histogram ----------
__global__ __launch_bounds__(256) void ip_count(const int4* __restrict__ index4,
                                                uint32_t* __restrict__ gcnt) {
    __shared__ uint32_t cnt[NB];
    const int t = threadIdx.x, blk = blockIdx.x;
    for (int i = t; i < NB; i += B_THR) cnt[i] = 0;
    __syncthreads();
    const int base4 = blk * (B_UPD / 4);
#pragma unroll
    for (int k = 0; k < 8; ++k) {
        int4 id = index4[base4 + t + k * B_THR];
        atomicAdd(&cnt[((uint32_t)id.x) >> LOGSLICE], 1u);
        atomicAdd(&cnt[((uint32_t)id.y) >> LOGSLICE], 1u);
        atomicAdd(&cnt[((uint32_t)id.z) >> LOGSLICE], 1u);
        atomicAdd(&cnt[((uint32_t)id.w) >> LOGSLICE], 1u);
    }
    __syncthreads();
    for (int i = t; i < NB; i += B_THR)
        gcnt[(size_t)blk * NB + i] = cnt[i];
}

// ---------- K2: exclusive scan over blocks, per bucket (in place) ----------
__global__ __launch_bounds__(256) void ip_scan_blocks(uint32_t* __restrict__ gcnt,
                                                      uint32_t* __restrict__ btotal, int B) {
    __shared__ uint32_t tmp[B_THR];
    const int t = threadIdx.x, b = blockIdx.x;
    uint32_t running = 0;
    for (int r = 0; r < B; r += B_THR) {
        const size_t slot = (size_t)(r + t) * NB + b;
        uint32_t v = gcnt[slot];
        tmp[t] = v; __syncthreads();
        for (int off = 1; off < B_THR; off <<= 1) {
            uint32_t u = (t >= off) ? tmp[t - off] : 0; __syncthreads();
            tmp[t] += u; __syncthreads();
        }
        uint32_t incl = tmp[t], tot = tmp[B_THR - 1];
        gcnt[slot] = running + (incl - v);
        running += tot;
        __syncthreads();
    }
    if (t == 0) btotal[b] = running;
}

// ---------- K3: exclusive scan over buckets ----------
__global__ __launch_bounds__(1024) void ip_scan_buckets(const uint32_t* __restrict__ btotal,
                                                        uint32_t* __restrict__ bbase) {
    __shared__ uint32_t tmp[NB];
    const int t = threadIdx.x;
    uint32_t v = btotal[t];
    tmp[t] = v; __syncthreads();
    for (int off = 1; off < NB; off <<= 1) {
        uint32_t u = (t >= off) ? tmp[t - off] : 0; __syncthreads();
        tmp[t] += u; __syncthreads();
    }
    bbase[t] = tmp[t] - v;
}

// ---------- K4: bin into bucket-contiguous pairs (no global atomics) ----------
__global__ __launch_bounds__(256) void ip_bin(const int4* __restrict__ index4,
                                              const int4* __restrict__ value4,
                                              const uint32_t* __restrict__ gcnt,
                                              const uint32_t* __restrict__ bbase,
                                              uint32_t* __restrict__ pairs) {
    __shared__ uint32_t cur[NB];       // counts -> lstart (then read-only)
    __shared__ uint32_t gbase[NB];
    __shared__ uint32_t sorted[B_UPD]; // 32 KiB
    __shared__ uint32_t tmp[B_THR];
    const int t = threadIdx.x, blk = blockIdx.x;

    for (int i = t; i < NB; i += B_THR) cur[i] = 0;
    __syncthreads();

    const int base4 = blk * (B_UPD / 4);
    int4 idx[8], val[8];
#pragma unroll
    for (int k = 0; k < 8; ++k) {
        idx[k] = index4[base4 + t + k * B_THR];
        val[k] = value4[base4 + t + k * B_THR];
    }
    uint32_t lrank[32];
#pragma unroll
    for (int k = 0; k < 8; ++k) {
        lrank[k * 4 + 0] = atomicAdd(&cur[((uint32_t)idx[k].x) >> LOGSLICE], 1u);
        lrank[k * 4 + 1] = atomicAdd(&cur[((uint32_t)idx[k].y) >> LOGSLICE], 1u);
        lrank[k * 4 + 2] = atomicAdd(&cur[((uint32_t)idx[k].z) >> LOGSLICE], 1u);
        lrank[k * 4 + 3] = atomicAdd(&cur[((uint32_t)idx[k].w) >> LOGSLICE], 1u);
    }
    __syncthreads();

    // gbase[i] = bucket base + this block's offset within bucket (coalesced reads)
    for (int r = 0; r < NB / B_THR; ++r) {
        int i = t + r * B_THR;
        gbase[i] = bbase[i] + gcnt[(size_t)blk * NB + i];
    }
    // exclusive scan of local counts -> lstart (4 consecutive buckets per thread)
    uint32_t c0 = cur[t * 4 + 0], c1 = cur[t * 4 + 1], c2 = cur[t * 4 + 2], c3 = cur[t * 4 + 3];
    uint32_t s = c0 + c1 + c2 + c3;
    tmp[t] = s; __syncthreads();
    for (int off = 1; off < B_THR; off <<= 1) {
        uint32_t u = (t >= off) ? tmp[t - off] : 0; __syncthreads();
        tmp[t] += u; __syncthreads();
    }
    uint32_t ex = tmp[t] - s;
    cur[t * 4 + 0] = ex;
    cur[t * 4 + 1] = ex + c0;
    cur[t * 4 + 2] = ex + c0 + c1;
    cur[t * 4 + 3] = ex + c0 + c1 + c2;
    __syncthreads();

    // place into LDS, grouped by bucket
#define PLACE(k, c, e)                                                              \
    {                                                                               \
        uint32_t ix = (uint32_t)idx[k].c;                                           \
        uint32_t b_ = ix >> LOGSLICE;                                               \
        sorted[cur[b_] + lrank[e]] =                                                \
            (((uint32_t)val[k].c) << LOGSLICE) | (ix & (SLICE - 1));                \
    }
#pragma unroll
    for (int k = 0; k < 8; ++k) {
        PLACE(k, x, k * 4 + 0) PLACE(k, y, k * 4 + 1)
        PLACE(k, z, k * 4 + 2) PLACE(k, w, k * 4 + 3)
    }
#undef PLACE
    __syncthreads();

    // write out bucket-contiguous runs; binary search bucket of position j
    for (int j = t; j < B_UPD; j += B_THR) {
        int lo = 0, hi = NB - 1;
        while (lo < hi) {
            int mid = (lo + hi + 1) >> 1;
            if (cur[mid] <= (uint32_t)j) lo = mid; else hi = mid - 1;
        }
        pairs[gbase[lo] + ((uint32_t)j - cur[lo])] = sorted[j];
    }
}

// ---------- K5: per-slice LDS accumulate, out = input + acc ----------
__global__ __launch_bounds__(512) void ip_accumulate(const uint32_t* __restrict__ pairs,
                                                     const uint32_t* __restrict__ btotal,
                                                     const uint32_t* __restrict__ bbase,
                                                     const int4* __restrict__ input4,
                                                     int4* __restrict__ out4) {
    __shared__ uint32_t acc[SLICE];    // 64 KiB
    const int b = blockIdx.x, t = threadIdx.x;
    for (int j = t; j < SLICE; j += blockDim.x) acc[j] = 0;
    __syncthreads();

    const uint32_t cnt = btotal[b];
    const uint32_t* __restrict__ p = pairs + bbase[b];
    for (uint32_t j = t; j < cnt; j += blockDim.x) {
        uint32_t pk = p[j];
        atomicAdd(&acc[pk & (SLICE - 1)], pk >> LOGSLICE);
    }
    __syncthreads();

    const int base4 = b * (SLICE / 4);
    for (int j = t; j < SLICE / 4; j += blockDim.x) {
        int4 in = input4[base4 + j];
        in.x += (int)acc[j * 4 + 0];
        in.y += (int)acc[j * 4 + 1];
        in.z += (int)acc[j * 4 + 2];
        in.w += (int)acc[j * 4 + 3];
        out4[base4 + j] = in;
    }
}

// ---------- fallback: direct atomics ----------
__global__ void ip_copy_kernel(const int4* __restrict__ in, int4* __restrict__ out, int n4) {
    int stride = gridDim.x * blockDim.x;
    for (int i = blockIdx.x * blockDim.x + threadIdx.x; i < n4; i += stride)
        out[i] = in[i];
}
__global__ void ip_scatter1_kernel(const int* __restrict__ index, const int* __restrict__ value,
                                   int* __restrict__ out, int m) {
    int stride = gridDim.x * blockDim.x;
    for (int i = blockIdx.x * blockDim.x + threadIdx.x; i < m; i += stride)
        atomicAdd(&out[index[i]], value[i]);
}

extern "C" void kernel_launch(void* const* d_in, const int* in_sizes, int n_in,
                              void* d_out, int out_size, void* d_ws, size_t ws_size,
                              hipStream_t stream) {
    const int* input = (const int*)d_in[0];
    const int* index = (const int*)d_in[1];
    const int* value = (const int*)d_in[2];
    int* out = (int*)d_out;

    const int N = in_sizes[0];
    const int M = in_sizes[1];
    const int B = M / B_UPD;   // bin/count blocks

    const size_t gcnt_bytes = (size_t)B * NB * sizeof(uint32_t);      // 16 MB
    const size_t tot_bytes  = NB * sizeof(uint32_t);
    const size_t need = gcnt_bytes + 2 * tot_bytes + (size_t)M * sizeof(uint32_t);

    const bool ok = (N == NB * SLICE) && (M % B_UPD == 0) && (B % B_THR == 0) &&
                    (ws_size >= need);

    if (ok) {
        uint32_t* gcnt   = (uint32_t*)d_ws;
        uint32_t* btotal = (uint32_t*)((char*)d_ws + gcnt_bytes);
        uint32_t* bbase  = btotal + NB;
        uint32_t* pairs  = bbase + NB;

        ip_count<<<B, B_THR, 0, stream>>>((const int4*)index, gcnt);
        ip_scan_blocks<<<NB, B_THR, 0, stream>>>(gcnt, btotal, B);
        ip_scan_buckets<<<1, NB, 0, stream>>>(btotal, bbase);
        ip_bin<<<B, B_THR, 0, stream>>>((const int4*)index, (const int4*)value,
                                        gcnt, bbase, pairs);
        ip_accumulate<<<NB, 512, 0, stream>>>(pairs, btotal, bbase,
                                              (const int4*)input, (int4*)out);
    } else {
        ip_copy_kernel<<<2048, 256, 0, stream>>>((const int4*)input, (int4*)d_out, N / 4);
        ip_scatter1_kernel<<<2048, 256, 0, stream>>>(index, value, out, M);
    }
}